// Round 12
// baseline (269.196 us; speedup 1.0000x reference)
//
#include <hip/hip_runtime.h>

#define N_NODES 100000
#define N_EDGES 300000
#define N_GRAPHS 4000
#define CAP 32

typedef float f32x4 __attribute__((ext_vector_type(4)));
typedef __bf16 bf16x8 __attribute__((ext_vector_type(8)));
typedef __bf16 bf16x2 __attribute__((ext_vector_type(2)));

// ---------------- workspace layout (float offsets) ----------------
static const size_t OFF_XA    = 0;                                   // N*16: x[9],as1[4],pad[3]
static const size_t OFF_AD4   = OFF_XA + (size_t)N_NODES * 16;       // N*4
static const size_t OFF_P2B   = OFF_AD4 + (size_t)N_NODES * 4;       // N*128 bf16 = N*64 floats
static const size_t OFF_ASAD2 = OFF_P2B + (size_t)N_NODES * 64;      // N*2
static const size_t OFF_WSB   = OFF_ASAD2 + (size_t)N_NODES * 2;     // 65536 bf16 = 32768 floats
static const size_t OFF_INVC  = OFF_WSB + 32768;                     // 4096 floats
static const size_t OFF_INT   = OFF_INVC + 4096;                     // deg[N], bucket[N*CAP]

// k_pre block partition (256 threads each)
#define PRE_NODE_END 391   // ceil(100000/256) node-pack blocks
#define PRE_PACKB_END 455  // +64: 16384 threads x 4 = 65536 W2 elements
#define PRE_DEG_END 846    // +391: zero deg[100000]
#define PRE_OUT_END 1346   // +500: zero out (128000 float4)
#define PRE_INV_END 1362   // +16: inv_cnt[4000]

__device__ __forceinline__ float lrelu(float x) { return x < 0.f ? 0.2f * x : x; }
__device__ __forceinline__ float elu(float x)   { return x > 0.f ? x : __expf(x) - 1.f; }

// Fat pre-kernel: node pack || W2 pack || deg zero || out zero || inv_cnt
__global__ __launch_bounds__(256) void k_pre(
    const float* __restrict__ x, const float* __restrict__ W1,
    const float* __restrict__ a_src1, const float* __restrict__ a_dst1,
    const float* __restrict__ W2, const int* __restrict__ batch,
    float* __restrict__ xa, float* __restrict__ ad4,
    __bf16* __restrict__ wsB, int* __restrict__ deg, float* __restrict__ out,
    float* __restrict__ inv_cnt) {
    int b = blockIdx.x, tid = threadIdx.x;
    if (b < PRE_NODE_END) {
        __shared__ float wf[72];
        if (tid < 72) {
            int isd = tid / 36, r = tid % 36, k = r / 4, h = r % 4;
            const float* a = isd ? a_dst1 : a_src1;
            float s = 0.f;
            for (int c = 0; c < 128; c++) s += W1[k * 512 + h * 128 + c] * a[h * 128 + c];
            wf[tid] = s;
        }
        __syncthreads();
        int n = b * 256 + tid;
        if (n >= N_NODES) return;
        float xv[9];
#pragma unroll
        for (int k = 0; k < 9; k++) xv[k] = x[n * 9 + k];
        float as[4], ad[4];
#pragma unroll
        for (int h = 0; h < 4; h++) {
            float s = 0.f, d = 0.f;
#pragma unroll
            for (int k = 0; k < 9; k++) {
                s += xv[k] * wf[k * 4 + h];
                d += xv[k] * wf[36 + k * 4 + h];
            }
            as[h] = s; ad[h] = d;
        }
        f32x4* xp = (f32x4*)(xa + (size_t)n * 16);
        xp[0] = (f32x4){xv[0], xv[1], xv[2], xv[3]};
        xp[1] = (f32x4){xv[4], xv[5], xv[6], xv[7]};
        xp[2] = (f32x4){xv[8], as[0], as[1], as[2]};
        xp[3] = (f32x4){as[3], 0.f, 0.f, 0.f};
        *(f32x4*)(ad4 + (size_t)n * 4) = (f32x4){ad[0], ad[1], ad[2], ad[3]};
    } else if (b < PRE_PACKB_END) {
        int t = (b - PRE_NODE_END) * 256 + tid;
#pragma unroll
        for (int m = 0; m < 4; m++) {
            int idx = t * 4 + m;                 // 0..65535
            int k = idx >> 7, nn = idx & 127;
            wsB[(size_t)nn * 512 + k] = (__bf16)W2[(size_t)k * 128 + nn];
        }
    } else if (b < PRE_DEG_END) {
        int idx = (b - PRE_PACKB_END) * 256 + tid;
        if (idx < N_NODES) deg[idx] = 0;
    } else if (b < PRE_OUT_END) {
        int idx = (b - PRE_DEG_END) * 256 + tid;  // < 128000 float4s
        if (idx < 128000) ((f32x4*)out)[idx] = (f32x4){0.f, 0.f, 0.f, 0.f};
    } else {
        int g = (b - PRE_OUT_END) * 256 + tid;
        if (g >= N_GRAPHS) return;
        int lo = 0, hi = N_NODES;
        while (lo < hi) { int mid = (lo + hi) >> 1; if (batch[mid] < g) lo = mid + 1; else hi = mid; }
        int s = lo; hi = N_NODES;
        while (lo < hi) { int mid = (lo + hi) >> 1; if (batch[mid] < g + 1) lo = mid + 1; else hi = mid; }
        int c = lo - s;
        inv_cnt[g] = 1.f / (float)(c > 0 ? c : 1);
    }
}

// build per-dst bucket of src ids
__global__ void k_bucket(const int* __restrict__ ei, int* __restrict__ deg,
                         int* __restrict__ bucket) {
    int e = blockIdx.x * 256 + threadIdx.x;
    if (e >= N_EDGES) return;
    int s = ei[e], d = ei[N_EDGES + e];
    int slot = atomicAdd(&deg[d], 1);
    if (slot < CAP) bucket[d * CAP + slot] = s;
}

// Mega GEMM, half-K double pass, 3 blocks/CU (LDS 50.1 KB):
//   phase 0: fused layer-1 aggregation (2 thr per node-head) + stage W1s(half0)
//   per half: phase 1 h2=elu(agg@W1+b1) from LDS-broadcast W1s -> bf16 As;
//             phase 2 MFMA (B inline from L2-hot wsB); half0's phase 2 also
//             stages W1s(half1) (W1s free after phase 1)
//   epilogue: p2b(bf16) + asad2 via LDS cross-wave reduction (red2 = AgT union)
__global__ __launch_bounds__(512, 6) void k_gemm(
    const float* __restrict__ xa, const float* __restrict__ ad4,
    const int* __restrict__ deg, const int* __restrict__ bucket,
    const float* __restrict__ W1, const float* __restrict__ b1,
    const __bf16* __restrict__ wsB,
    const float* __restrict__ a_src2, const float* __restrict__ a_dst2,
    __bf16* __restrict__ p2b, float* __restrict__ asad2) {
    __shared__ __bf16 As[64 * 256];    // 32 KB, frag-major: tile t=rt*8+kg, lane*8
    __shared__ float W1s[9 * 260];     // 9.4 KB (stride 260 floats = 1040 B, 16B-aligned rows)
    __shared__ __bf16 AgT[64 * 72];    // 9.2 KB; reused as red2 (4 KB) in epilogue
    float* red2 = (float*)AgT;
    const int tid = threadIdx.x;
    const int lane = tid & 63;
    const int w = tid >> 6;
    const int i = lane & 15;
    const int q = lane >> 4;
    const int m0 = blockIdx.x * 64;

    // ---- stage W1s for half 0 (all threads; overlaps phase-0 gather) ----
    for (int idx = tid; idx < 2304; idx += 512) {
        int k = idx >> 8, j = idx & 255;
        W1s[k * 260 + j] = W1[k * 512 + j];
    }

    // ---- phase 0: fused layer-1 aggregation, 2 threads per (node,head) ----
    {
        int nh = tid >> 1, sub = tid & 1;
        int r = nh >> 2, h = nh & 3;
        int n = m0 + r;
        float acc[9] = {};
        float z = 0.f;
        bool valid = (n < N_NODES);
        if (valid) {
            float ad = ad4[(size_t)n * 4 + h];
            int dg = deg[n];
            if (dg > CAP) dg = CAP;
            if (sub == 0) {  // self loop
                const f32x4* xp = (const f32x4*)(xa + (size_t)n * 16);
                f32x4 v0 = xp[0], v1 = xp[1], v2 = xp[2], v3 = xp[3];
                float asl = (h == 0) ? v2.y : (h == 1) ? v2.z : (h == 2) ? v2.w : v3.x;
                float e = __expf(lrelu(asl + ad));
                z += e;
                acc[0] += e * v0.x; acc[1] += e * v0.y; acc[2] += e * v0.z; acc[3] += e * v0.w;
                acc[4] += e * v1.x; acc[5] += e * v1.y; acc[6] += e * v1.z; acc[7] += e * v1.w;
                acc[8] += e * v2.x;
            }
            for (int j = sub; j < dg; j += 2) {
                int src = bucket[n * CAP + j];
                const f32x4* xp = (const f32x4*)(xa + (size_t)src * 16);
                f32x4 v0 = xp[0], v1 = xp[1], v2 = xp[2], v3 = xp[3];
                float asl = (h == 0) ? v2.y : (h == 1) ? v2.z : (h == 2) ? v2.w : v3.x;
                float e = __expf(lrelu(asl + ad));
                z += e;
                acc[0] += e * v0.x; acc[1] += e * v0.y; acc[2] += e * v0.z; acc[3] += e * v0.w;
                acc[4] += e * v1.x; acc[5] += e * v1.y; acc[6] += e * v1.z; acc[7] += e * v1.w;
                acc[8] += e * v2.x;
            }
        }
        z += __shfl_xor(z, 1);
#pragma unroll
        for (int k = 0; k < 9; k++) acc[k] += __shfl_xor(acc[k], 1);
        if (sub == 0) {
            float inv = valid ? 1.f / z : 0.f;
            bf16x8 p0;
#pragma unroll
            for (int k = 0; k < 8; k++) p0[k] = (__bf16)(acc[k] * inv);
            __bf16* dst = AgT + r * 72 + h * 16;
            *(bf16x8*)dst = p0;
            dst[8] = (__bf16)(acc[8] * inv);
        }
    }
    __syncthreads();

    f32x4 acc[4];
#pragma unroll
    for (int r = 0; r < 4; r++) acc[r] = (f32x4){0.f, 0.f, 0.f, 0.f};

    const int row = tid & 63;
    const int kg = __builtin_amdgcn_readfirstlane(tid >> 6);  // wave-uniform
    const int rt_p1 = row >> 4, il = row & 15;
    const __bf16* bcol = wsB + (size_t)(w * 16 + i) * 512 + q * 8;

#pragma unroll
    for (int half = 0; half < 2; half++) {
        // B slice for this half (compiler may keep in regs or re-load from L2 — ok)
        bf16x8 breg[8];
#pragma unroll
        for (int kc = 0; kc < 8; kc++)
            breg[kc] = *(const bf16x8*)(bcol + half * 256 + kc * 32);

        // ---- phase 1: h2 for 256 cols; thread = (row, kg: 32-col group) ----
        {
            int h = half * 2 + (kg >> 2);
            float ag[9];
            {
                bf16x8 a8 = *(const bf16x8*)&AgT[row * 72 + h * 16];
#pragma unroll
                for (int k = 0; k < 8; k++) ag[k] = (float)a8[k];
                ag[8] = (float)AgT[row * 72 + h * 16 + 8];
            }
#pragma unroll
            for (int c8 = 0; c8 < 4; c8++) {
                int jr = kg * 32 + c8 * 8;             // col within half
                int j0 = half * 256 + jr;              // global h2 col
                float o[8];
#pragma unroll
                for (int e = 0; e < 8; e++) o[e] = b1[j0 + e];
#pragma unroll
                for (int k = 0; k < 9; k++) {
                    f32x4 wa = *(const f32x4*)&W1s[k * 260 + jr];       // broadcast
                    f32x4 wb = *(const f32x4*)&W1s[k * 260 + jr + 4];
                    o[0] += ag[k] * wa.x; o[1] += ag[k] * wa.y;
                    o[2] += ag[k] * wa.z; o[3] += ag[k] * wa.w;
                    o[4] += ag[k] * wb.x; o[5] += ag[k] * wb.y;
                    o[6] += ag[k] * wb.z; o[7] += ag[k] * wb.w;
                }
                bf16x8 pk;
#pragma unroll
                for (int e = 0; e < 8; e++) pk[e] = (__bf16)elu(o[e]);
                *(bf16x8*)&As[(rt_p1 * 8 + kg) * 512 + (c8 * 16 + il) * 8] = pk;
            }
        }
        __syncthreads();   // As + W1s readers done

        // half0's phase 2 also stages W1s for half 1 (W1s free after phase 1)
        if (half == 0) {
            for (int idx = tid; idx < 2304; idx += 512) {
                int k = idx >> 8, j = idx & 255;
                W1s[k * 260 + j] = W1[k * 512 + 256 + j];
            }
        }

        // ---- phase 2: MFMA sweep over this half's 8 kc-tiles ----
#pragma unroll
        for (int kc = 0; kc < 8; kc++) {
#pragma unroll
            for (int rt = 0; rt < 4; rt++) {
                bf16x8 af = *(const bf16x8*)&As[(rt * 8 + kc) * 512 + lane * 8];
                acc[rt] = __builtin_amdgcn_mfma_f32_16x16x32_bf16(af, breg[kc], acc[rt], 0, 0, 0);
            }
        }
        __syncthreads();   // As reused next half; W1s(1) writes visible
    }

    // ---- epilogue: p2b + asad2 via LDS cross-wave reduction (red2 = AgT) ----
    float as2 = a_src2[w * 16 + i];
    float ad2 = a_dst2[w * 16 + i];
#pragma unroll
    for (int rt = 0; rt < 4; rt++) {
#pragma unroll
        for (int qq = 0; qq < 4; qq++) {
            int r2 = rt * 16 + q * 4 + qq;
            float v = acc[rt][qq];
            if (m0 + r2 < N_NODES)
                p2b[(size_t)(m0 + r2) * 128 + w * 16 + i] = (__bf16)v;
            float s = v * as2, d = v * ad2;
#pragma unroll
            for (int off = 1; off < 16; off <<= 1) {
                s += __shfl_xor(s, off);
                d += __shfl_xor(d, off);
            }
            if (i == 0) {
                red2[r2 * 16 + w * 2] = s;
                red2[r2 * 16 + w * 2 + 1] = d;
            }
        }
    }
    __syncthreads();
    if (tid < 128) {
        int r2 = tid >> 1, cc = tid & 1;
        float sum = 0.f;
#pragma unroll
        for (int ww = 0; ww < 8; ww++) sum += red2[r2 * 16 + ww * 2 + cc];
        if (m0 + r2 < N_NODES) asad2[(size_t)(m0 + r2) * 2 + cc] = sum;
    }
}

// Layer-2 attention + aggregation + elu + fused graph-MEAN.
// ONE WAVE PER NODE; neighbors processed in chunks of 4 with all loads
// issued before use (4x memory-level parallelism); per-node atomic flush.
__global__ void k_agg2_pool(const __bf16* __restrict__ p2b, const float* __restrict__ asad2,
                            const int* __restrict__ deg, const int* __restrict__ bucket,
                            const float* __restrict__ b2, const int* __restrict__ batch,
                            const float* __restrict__ inv_cnt, float* __restrict__ out) {
    int n = (blockIdx.x * 256 + threadIdx.x) >> 6;
    n = __builtin_amdgcn_readfirstlane(n);
    int lane = threadIdx.x & 63;
    if (n >= N_NODES) return;
    float ad = asad2[n * 2 + 1];
    float e = __expf(lrelu(asad2[n * 2] + ad));  // self loop
    float z = e;
    bf16x2 v = ((const bf16x2*)(p2b + (size_t)n * 128))[lane];
    float a0 = e * (float)v.x;
    float a1 = e * (float)v.y;
    int dg = deg[n];
    if (dg > CAP) dg = CAP;
    for (int j = 0; j < dg; j += 4) {
        int s0 = bucket[n * CAP + j];
        int s1 = bucket[n * CAP + min(j + 1, dg - 1)];
        int s2 = bucket[n * CAP + min(j + 2, dg - 1)];
        int s3 = bucket[n * CAP + min(j + 3, dg - 1)];
        float l0 = asad2[s0 * 2], l1 = asad2[s1 * 2];
        float l2 = asad2[s2 * 2], l3 = asad2[s3 * 2];
        bf16x2 w0 = ((const bf16x2*)(p2b + (size_t)s0 * 128))[lane];
        bf16x2 w1 = ((const bf16x2*)(p2b + (size_t)s1 * 128))[lane];
        bf16x2 w2 = ((const bf16x2*)(p2b + (size_t)s2 * 128))[lane];
        bf16x2 w3 = ((const bf16x2*)(p2b + (size_t)s3 * 128))[lane];
        float e0 = __expf(lrelu(l0 + ad));
        float e1 = (j + 1 < dg) ? __expf(lrelu(l1 + ad)) : 0.f;
        float e2 = (j + 2 < dg) ? __expf(lrelu(l2 + ad)) : 0.f;
        float e3 = (j + 3 < dg) ? __expf(lrelu(l3 + ad)) : 0.f;
        z += e0 + e1 + e2 + e3;
        a0 += e0 * (float)w0.x + e1 * (float)w1.x + e2 * (float)w2.x + e3 * (float)w3.x;
        a1 += e0 * (float)w0.y + e1 * (float)w1.y + e2 * (float)w2.y + e3 * (float)w3.y;
    }
    float inv = 1.f / z;
    int g = batch[n];
    float ic = inv_cnt[g];
    atomicAdd(&out[(size_t)g * 128 + 2 * lane], elu(a0 * inv + b2[2 * lane]) * ic);
    atomicAdd(&out[(size_t)g * 128 + 2 * lane + 1], elu(a1 * inv + b2[2 * lane + 1]) * ic);
}

extern "C" void kernel_launch(void* const* d_in, const int* in_sizes, int n_in,
                              void* d_out, int out_size, void* d_ws, size_t ws_size,
                              hipStream_t stream) {
    const float* x       = (const float*)d_in[0];
    const int*   ei      = (const int*)d_in[1];
    const int*   batch   = (const int*)d_in[2];
    const float* W1      = (const float*)d_in[3];
    const float* a_src1  = (const float*)d_in[4];
    const float* a_dst1  = (const float*)d_in[5];
    const float* b1      = (const float*)d_in[6];
    const float* W2      = (const float*)d_in[7];
    const float* a_src2  = (const float*)d_in[8];
    const float* a_dst2  = (const float*)d_in[9];
    const float* b2      = (const float*)d_in[10];
    float* out = (float*)d_out;

    float* wsf   = (float*)d_ws;
    float* xa    = wsf + OFF_XA;
    float* ad4   = wsf + OFF_AD4;
    __bf16* p2b  = (__bf16*)(wsf + OFF_P2B);
    float* asad2 = wsf + OFF_ASAD2;
    __bf16* wsB  = (__bf16*)(wsf + OFF_WSB);
    float* invc  = wsf + OFF_INVC;
    int* wsi    = (int*)(wsf + OFF_INT);
    int* deg    = wsi;
    int* bucket = wsi + N_NODES;

    k_pre<<<PRE_INV_END, 256, 0, stream>>>(x, W1, a_src1, a_dst1, W2, batch,
                                           xa, ad4, wsB, deg, out, invc);
    k_bucket<<<(N_EDGES + 255) / 256, 256, 0, stream>>>(ei, deg, bucket);
    k_gemm<<<(N_NODES + 63) / 64, 512, 0, stream>>>(xa, ad4, deg, bucket, W1, b1,
                                                    wsB, a_src2, a_dst2, p2b, asad2);
    k_agg2_pool<<<((size_t)N_NODES * 64 + 255) / 256, 256, 0, stream>>>(
        p2b, asad2, deg, bucket, b2, batch, invc, out);
}

// Round 13
// 233.439 us; speedup vs baseline: 1.1532x; 1.1532x over previous
//
#include <hip/hip_runtime.h>

#define N_NODES 100000
#define N_EDGES 300000
#define N_GRAPHS 4000
#define CAP 32

typedef float f32x4 __attribute__((ext_vector_type(4)));
typedef __bf16 bf16x8 __attribute__((ext_vector_type(8)));
typedef __bf16 bf16x2 __attribute__((ext_vector_type(2)));

// ---------------- workspace layout (float offsets) ----------------
static const size_t OFF_XA    = 0;                                   // N*16: x[9],as1[4],pad[3]
static const size_t OFF_AD4   = OFF_XA + (size_t)N_NODES * 16;       // N*4
static const size_t OFF_P2B   = OFF_AD4 + (size_t)N_NODES * 4;       // N*128 bf16 = N*64 floats
static const size_t OFF_ASAD2 = OFF_P2B + (size_t)N_NODES * 64;      // N*2
static const size_t OFF_WSB   = OFF_ASAD2 + (size_t)N_NODES * 2;     // 65536 bf16 = 32768 floats
static const size_t OFF_GST   = OFF_WSB + 32768;                     // gstart[4001] (ints, 4096 slot)
static const size_t OFF_INT   = OFF_GST + 4096;                      // deg[N], bucket[N*CAP]

// k_pre block partition (256 threads each)
#define PRE_NODE_END 391   // ceil(100000/256) node-pack blocks
#define PRE_PACKB_END 455  // +64: 16384 threads x 4 = 65536 W2 elements
#define PRE_DEG_END 846    // +391: zero deg[100000]
#define PRE_GST_END 862    // +16: gstart[0..4000] via binary search

__device__ __forceinline__ float lrelu(float x) { return x < 0.f ? 0.2f * x : x; }
__device__ __forceinline__ float elu(float x)   { return x > 0.f ? x : __expf(x) - 1.f; }

// Fat pre-kernel: node pack || W2 pack || deg zero || gstart
__global__ __launch_bounds__(256) void k_pre(
    const float* __restrict__ x, const float* __restrict__ W1,
    const float* __restrict__ a_src1, const float* __restrict__ a_dst1,
    const float* __restrict__ W2, const int* __restrict__ batch,
    float* __restrict__ xa, float* __restrict__ ad4,
    __bf16* __restrict__ wsB, int* __restrict__ deg, int* __restrict__ gstart) {
    int b = blockIdx.x, tid = threadIdx.x;
    if (b < PRE_NODE_END) {
        __shared__ float wf[72];
        if (tid < 72) {
            int isd = tid / 36, r = tid % 36, k = r / 4, h = r % 4;
            const float* a = isd ? a_dst1 : a_src1;
            float s = 0.f;
            for (int c = 0; c < 128; c++) s += W1[k * 512 + h * 128 + c] * a[h * 128 + c];
            wf[tid] = s;
        }
        __syncthreads();
        int n = b * 256 + tid;
        if (n >= N_NODES) return;
        float xv[9];
#pragma unroll
        for (int k = 0; k < 9; k++) xv[k] = x[n * 9 + k];
        float as[4], ad[4];
#pragma unroll
        for (int h = 0; h < 4; h++) {
            float s = 0.f, d = 0.f;
#pragma unroll
            for (int k = 0; k < 9; k++) {
                s += xv[k] * wf[k * 4 + h];
                d += xv[k] * wf[36 + k * 4 + h];
            }
            as[h] = s; ad[h] = d;
        }
        f32x4* xp = (f32x4*)(xa + (size_t)n * 16);
        xp[0] = (f32x4){xv[0], xv[1], xv[2], xv[3]};
        xp[1] = (f32x4){xv[4], xv[5], xv[6], xv[7]};
        xp[2] = (f32x4){xv[8], as[0], as[1], as[2]};
        xp[3] = (f32x4){as[3], 0.f, 0.f, 0.f};
        *(f32x4*)(ad4 + (size_t)n * 4) = (f32x4){ad[0], ad[1], ad[2], ad[3]};
    } else if (b < PRE_PACKB_END) {
        int t = (b - PRE_NODE_END) * 256 + tid;
#pragma unroll
        for (int m = 0; m < 4; m++) {
            int idx = t * 4 + m;                 // 0..65535
            int k = idx >> 7, nn = idx & 127;
            wsB[(size_t)nn * 512 + k] = (__bf16)W2[(size_t)k * 128 + nn];
        }
    } else if (b < PRE_DEG_END) {
        int idx = (b - PRE_PACKB_END) * 256 + tid;
        if (idx < N_NODES) deg[idx] = 0;
    } else {
        int g = (b - PRE_DEG_END) * 256 + tid;
        if (g > N_GRAPHS) return;
        int lo = 0, hi = N_NODES;
        while (lo < hi) { int mid = (lo + hi) >> 1; if (batch[mid] < g) lo = mid + 1; else hi = mid; }
        gstart[g] = lo;
    }
}

// build per-dst bucket of src ids
__global__ void k_bucket(const int* __restrict__ ei, int* __restrict__ deg,
                         int* __restrict__ bucket) {
    int e = blockIdx.x * 256 + threadIdx.x;
    if (e >= N_EDGES) return;
    int s = ei[e], d = ei[N_EDGES + e];
    int slot = atomicAdd(&deg[d], 1);
    if (slot < CAP) bucket[d * CAP + slot] = s;
}

// Mega GEMM, half-K double pass, 3 blocks/CU (LDS 50.1 KB):
//   phase 0: fused layer-1 aggregation (2 thr per node-head) + stage W1s(half0)
//   per half: phase 1 h2=elu(agg@W1+b1) from LDS-broadcast W1s -> bf16 As;
//             phase 2 MFMA (B inline from L2-hot wsB); half0's phase 2 also
//             stages W1s(half1)
//   epilogue: p2b(bf16) + asad2 via LDS cross-wave reduction (red2 = AgT union)
__global__ __launch_bounds__(512, 6) void k_gemm(
    const float* __restrict__ xa, const float* __restrict__ ad4,
    const int* __restrict__ deg, const int* __restrict__ bucket,
    const float* __restrict__ W1, const float* __restrict__ b1,
    const __bf16* __restrict__ wsB,
    const float* __restrict__ a_src2, const float* __restrict__ a_dst2,
    __bf16* __restrict__ p2b, float* __restrict__ asad2) {
    __shared__ __bf16 As[64 * 256];    // 32 KB, frag-major: tile t=rt*8+kg, lane*8
    __shared__ float W1s[9 * 260];     // 9.4 KB
    __shared__ __bf16 AgT[64 * 72];    // 9.2 KB; reused as red2 in epilogue
    float* red2 = (float*)AgT;
    const int tid = threadIdx.x;
    const int lane = tid & 63;
    const int w = tid >> 6;
    const int i = lane & 15;
    const int q = lane >> 4;
    const int m0 = blockIdx.x * 64;

    // ---- stage W1s for half 0 (overlaps phase-0 gather) ----
    for (int idx = tid; idx < 2304; idx += 512) {
        int k = idx >> 8, j = idx & 255;
        W1s[k * 260 + j] = W1[k * 512 + j];
    }

    // ---- phase 0: fused layer-1 aggregation, 2 threads per (node,head) ----
    {
        int nh = tid >> 1, sub = tid & 1;
        int r = nh >> 2, h = nh & 3;
        int n = m0 + r;
        float acc[9] = {};
        float z = 0.f;
        bool valid = (n < N_NODES);
        if (valid) {
            float ad = ad4[(size_t)n * 4 + h];
            int dg = deg[n];
            if (dg > CAP) dg = CAP;
            if (sub == 0) {  // self loop
                const f32x4* xp = (const f32x4*)(xa + (size_t)n * 16);
                f32x4 v0 = xp[0], v1 = xp[1], v2 = xp[2], v3 = xp[3];
                float asl = (h == 0) ? v2.y : (h == 1) ? v2.z : (h == 2) ? v2.w : v3.x;
                float e = __expf(lrelu(asl + ad));
                z += e;
                acc[0] += e * v0.x; acc[1] += e * v0.y; acc[2] += e * v0.z; acc[3] += e * v0.w;
                acc[4] += e * v1.x; acc[5] += e * v1.y; acc[6] += e * v1.z; acc[7] += e * v1.w;
                acc[8] += e * v2.x;
            }
            for (int j = sub; j < dg; j += 2) {
                int src = bucket[n * CAP + j];
                const f32x4* xp = (const f32x4*)(xa + (size_t)src * 16);
                f32x4 v0 = xp[0], v1 = xp[1], v2 = xp[2], v3 = xp[3];
                float asl = (h == 0) ? v2.y : (h == 1) ? v2.z : (h == 2) ? v2.w : v3.x;
                float e = __expf(lrelu(asl + ad));
                z += e;
                acc[0] += e * v0.x; acc[1] += e * v0.y; acc[2] += e * v0.z; acc[3] += e * v0.w;
                acc[4] += e * v1.x; acc[5] += e * v1.y; acc[6] += e * v1.z; acc[7] += e * v1.w;
                acc[8] += e * v2.x;
            }
        }
        z += __shfl_xor(z, 1);
#pragma unroll
        for (int k = 0; k < 9; k++) acc[k] += __shfl_xor(acc[k], 1);
        if (sub == 0) {
            float inv = valid ? 1.f / z : 0.f;
            bf16x8 p0;
#pragma unroll
            for (int k = 0; k < 8; k++) p0[k] = (__bf16)(acc[k] * inv);
            __bf16* dst = AgT + r * 72 + h * 16;
            *(bf16x8*)dst = p0;
            dst[8] = (__bf16)(acc[8] * inv);
        }
    }
    __syncthreads();

    f32x4 acc[4];
#pragma unroll
    for (int r = 0; r < 4; r++) acc[r] = (f32x4){0.f, 0.f, 0.f, 0.f};

    const int row = tid & 63;
    const int kg = __builtin_amdgcn_readfirstlane(tid >> 6);  // wave-uniform
    const int rt_p1 = row >> 4, il = row & 15;
    const __bf16* bcol = wsB + (size_t)(w * 16 + i) * 512 + q * 8;

#pragma unroll
    for (int half = 0; half < 2; half++) {
        bf16x8 breg[8];
#pragma unroll
        for (int kc = 0; kc < 8; kc++)
            breg[kc] = *(const bf16x8*)(bcol + half * 256 + kc * 32);

        // ---- phase 1: h2 for 256 cols; thread = (row, kg: 32-col group) ----
        {
            int h = half * 2 + (kg >> 2);
            float ag[9];
            {
                bf16x8 a8 = *(const bf16x8*)&AgT[row * 72 + h * 16];
#pragma unroll
                for (int k = 0; k < 8; k++) ag[k] = (float)a8[k];
                ag[8] = (float)AgT[row * 72 + h * 16 + 8];
            }
#pragma unroll
            for (int c8 = 0; c8 < 4; c8++) {
                int jr = kg * 32 + c8 * 8;
                int j0 = half * 256 + jr;
                float o[8];
#pragma unroll
                for (int e = 0; e < 8; e++) o[e] = b1[j0 + e];
#pragma unroll
                for (int k = 0; k < 9; k++) {
                    f32x4 wa = *(const f32x4*)&W1s[k * 260 + jr];
                    f32x4 wb = *(const f32x4*)&W1s[k * 260 + jr + 4];
                    o[0] += ag[k] * wa.x; o[1] += ag[k] * wa.y;
                    o[2] += ag[k] * wa.z; o[3] += ag[k] * wa.w;
                    o[4] += ag[k] * wb.x; o[5] += ag[k] * wb.y;
                    o[6] += ag[k] * wb.z; o[7] += ag[k] * wb.w;
                }
                bf16x8 pk;
#pragma unroll
                for (int e = 0; e < 8; e++) pk[e] = (__bf16)elu(o[e]);
                *(bf16x8*)&As[(rt_p1 * 8 + kg) * 512 + (c8 * 16 + il) * 8] = pk;
            }
        }
        __syncthreads();

        if (half == 0) {
            for (int idx = tid; idx < 2304; idx += 512) {
                int k = idx >> 8, j = idx & 255;
                W1s[k * 260 + j] = W1[k * 512 + 256 + j];
            }
        }

        // ---- phase 2: MFMA sweep over this half's 8 kc-tiles ----
#pragma unroll
        for (int kc = 0; kc < 8; kc++) {
#pragma unroll
            for (int rt = 0; rt < 4; rt++) {
                bf16x8 af = *(const bf16x8*)&As[(rt * 8 + kc) * 512 + lane * 8];
                acc[rt] = __builtin_amdgcn_mfma_f32_16x16x32_bf16(af, breg[kc], acc[rt], 0, 0, 0);
            }
        }
        __syncthreads();
    }

    // ---- epilogue: p2b + asad2 via LDS cross-wave reduction ----
    float as2 = a_src2[w * 16 + i];
    float ad2 = a_dst2[w * 16 + i];
#pragma unroll
    for (int rt = 0; rt < 4; rt++) {
#pragma unroll
        for (int qq = 0; qq < 4; qq++) {
            int r2 = rt * 16 + q * 4 + qq;
            float v = acc[rt][qq];
            if (m0 + r2 < N_NODES)
                p2b[(size_t)(m0 + r2) * 128 + w * 16 + i] = (__bf16)v;
            float s = v * as2, d = v * ad2;
#pragma unroll
            for (int off = 1; off < 16; off <<= 1) {
                s += __shfl_xor(s, off);
                d += __shfl_xor(d, off);
            }
            if (i == 0) {
                red2[r2 * 16 + w * 2] = s;
                red2[r2 * 16 + w * 2 + 1] = d;
            }
        }
    }
    __syncthreads();
    if (tid < 128) {
        int r2 = tid >> 1, cc = tid & 1;
        float sum = 0.f;
#pragma unroll
        for (int ww = 0; ww < 8; ww++) sum += red2[r2 * 16 + ww * 2 + cc];
        if (m0 + r2 < N_NODES) asad2[(size_t)(m0 + r2) * 2 + cc] = sum;
    }
}

// Layer-2 attention + aggregation + elu + graph-mean.
// ONE WAVE PER GRAPH (batch sorted, gstart precomputed): accumulate the whole
// graph in registers, plain-store out[g] — ZERO atomics. Chunk-4 neighbor MLP.
__global__ void k_agg2_pool(const __bf16* __restrict__ p2b, const float* __restrict__ asad2,
                            const int* __restrict__ deg, const int* __restrict__ bucket,
                            const float* __restrict__ b2, const int* __restrict__ gstart,
                            float* __restrict__ out) {
    int g = (blockIdx.x * 256 + threadIdx.x) >> 6;
    g = __builtin_amdgcn_readfirstlane(g);
    if (g >= N_GRAPHS) return;
    int lane = threadIdx.x & 63;
    int s0n = gstart[g], e0n = gstart[g + 1];
    float b2a = b2[2 * lane], b2b = b2[2 * lane + 1];
    float g0 = 0.f, g1 = 0.f;
    for (int n = s0n; n < e0n; n++) {
        float ad = asad2[n * 2 + 1];
        float e = __expf(lrelu(asad2[n * 2] + ad));  // self loop
        float z = e;
        bf16x2 v = ((const bf16x2*)(p2b + (size_t)n * 128))[lane];
        float a0 = e * (float)v.x;
        float a1 = e * (float)v.y;
        int dg = deg[n];
        if (dg > CAP) dg = CAP;
        for (int j = 0; j < dg; j += 4) {
            int s0 = bucket[n * CAP + j];
            int s1 = bucket[n * CAP + min(j + 1, dg - 1)];
            int s2 = bucket[n * CAP + min(j + 2, dg - 1)];
            int s3 = bucket[n * CAP + min(j + 3, dg - 1)];
            float l0 = asad2[s0 * 2], l1 = asad2[s1 * 2];
            float l2 = asad2[s2 * 2], l3 = asad2[s3 * 2];
            bf16x2 w0 = ((const bf16x2*)(p2b + (size_t)s0 * 128))[lane];
            bf16x2 w1 = ((const bf16x2*)(p2b + (size_t)s1 * 128))[lane];
            bf16x2 w2 = ((const bf16x2*)(p2b + (size_t)s2 * 128))[lane];
            bf16x2 w3 = ((const bf16x2*)(p2b + (size_t)s3 * 128))[lane];
            float e0 = __expf(lrelu(l0 + ad));
            float e1 = (j + 1 < dg) ? __expf(lrelu(l1 + ad)) : 0.f;
            float e2 = (j + 2 < dg) ? __expf(lrelu(l2 + ad)) : 0.f;
            float e3 = (j + 3 < dg) ? __expf(lrelu(l3 + ad)) : 0.f;
            z += e0 + e1 + e2 + e3;
            a0 += e0 * (float)w0.x + e1 * (float)w1.x + e2 * (float)w2.x + e3 * (float)w3.x;
            a1 += e0 * (float)w0.y + e1 * (float)w1.y + e2 * (float)w2.y + e3 * (float)w3.y;
        }
        float inv = 1.f / z;
        g0 += elu(a0 * inv + b2a);
        g1 += elu(a1 * inv + b2b);
    }
    int cnt = e0n - s0n;
    float ic = 1.f / (float)(cnt > 0 ? cnt : 1);
    out[(size_t)g * 128 + 2 * lane] = g0 * ic;
    out[(size_t)g * 128 + 2 * lane + 1] = g1 * ic;
}

extern "C" void kernel_launch(void* const* d_in, const int* in_sizes, int n_in,
                              void* d_out, int out_size, void* d_ws, size_t ws_size,
                              hipStream_t stream) {
    const float* x       = (const float*)d_in[0];
    const int*   ei      = (const int*)d_in[1];
    const int*   batch   = (const int*)d_in[2];
    const float* W1      = (const float*)d_in[3];
    const float* a_src1  = (const float*)d_in[4];
    const float* a_dst1  = (const float*)d_in[5];
    const float* b1      = (const float*)d_in[6];
    const float* W2      = (const float*)d_in[7];
    const float* a_src2  = (const float*)d_in[8];
    const float* a_dst2  = (const float*)d_in[9];
    const float* b2      = (const float*)d_in[10];
    float* out = (float*)d_out;

    float* wsf   = (float*)d_ws;
    float* xa    = wsf + OFF_XA;
    float* ad4   = wsf + OFF_AD4;
    __bf16* p2b  = (__bf16*)(wsf + OFF_P2B);
    float* asad2 = wsf + OFF_ASAD2;
    __bf16* wsB  = (__bf16*)(wsf + OFF_WSB);
    int* gstart  = (int*)(wsf + OFF_GST);
    int* wsi    = (int*)(wsf + OFF_INT);
    int* deg    = wsi;
    int* bucket = wsi + N_NODES;

    k_pre<<<PRE_GST_END, 256, 0, stream>>>(x, W1, a_src1, a_dst1, W2, batch,
                                           xa, ad4, wsB, deg, gstart);
    k_bucket<<<(N_EDGES + 255) / 256, 256, 0, stream>>>(ei, deg, bucket);
    k_gemm<<<(N_NODES + 63) / 64, 512, 0, stream>>>(xa, ad4, deg, bucket, W1, b1,
                                                    wsB, a_src2, a_dst2, p2b, asad2);
    k_agg2_pool<<<(N_GRAPHS * 64) / 256, 256, 0, stream>>>(
        p2b, asad2, deg, bucket, b2, gstart, out);
}

// Round 14
// 218.094 us; speedup vs baseline: 1.2343x; 1.0704x over previous
//
#include <hip/hip_runtime.h>

#define N_NODES 100000
#define N_EDGES 300000
#define N_GRAPHS 4000
#define CAP 32

typedef float f32x4 __attribute__((ext_vector_type(4)));
typedef __bf16 bf16x8 __attribute__((ext_vector_type(8)));
typedef __bf16 bf16x2 __attribute__((ext_vector_type(2)));

// ---------------- workspace layout (float offsets) ----------------
static const size_t OFF_XA    = 0;                                   // N*16
static const size_t OFF_AD4   = OFF_XA + (size_t)N_NODES * 16;       // N*4
static const size_t OFF_P2B   = OFF_AD4 + (size_t)N_NODES * 4;       // N*128 bf16
static const size_t OFF_ASAD2 = OFF_P2B + (size_t)N_NODES * 64;      // N*2
static const size_t OFF_H3B   = OFF_ASAD2 + (size_t)N_NODES * 2;     // N*128 bf16
static const size_t OFF_WSB   = OFF_H3B + (size_t)N_NODES * 64;      // 65536 bf16
static const size_t OFF_GST   = OFF_WSB + 32768;                     // gstart[4001]
static const size_t OFF_INT   = OFF_GST + 4096;                      // deg[N], bucket[N*CAP]

// k_pre block partition (256 threads each)
#define PRE_NODE_END 391   // ceil(100000/256)
#define PRE_PACKB_END 455  // +64: W2 pack
#define PRE_DEG_END 846    // +391: zero deg
#define PRE_GST_END 862    // +16: gstart

__device__ __forceinline__ float lrelu(float x) { return x < 0.f ? 0.2f * x : x; }
__device__ __forceinline__ float elu(float x)   { return x > 0.f ? x : __expf(x) - 1.f; }

// Fat pre-kernel: node pack || W2 pack || deg zero || gstart
__global__ __launch_bounds__(256) void k_pre(
    const float* __restrict__ x, const float* __restrict__ W1,
    const float* __restrict__ a_src1, const float* __restrict__ a_dst1,
    const float* __restrict__ W2, const int* __restrict__ batch,
    float* __restrict__ xa, float* __restrict__ ad4,
    __bf16* __restrict__ wsB, int* __restrict__ deg, int* __restrict__ gstart) {
    int b = blockIdx.x, tid = threadIdx.x;
    if (b < PRE_NODE_END) {
        __shared__ float wf[72];
        if (tid < 72) {
            int isd = tid / 36, r = tid % 36, k = r / 4, h = r % 4;
            const float* a = isd ? a_dst1 : a_src1;
            float s = 0.f;
            for (int c = 0; c < 128; c++) s += W1[k * 512 + h * 128 + c] * a[h * 128 + c];
            wf[tid] = s;
        }
        __syncthreads();
        int n = b * 256 + tid;
        if (n >= N_NODES) return;
        float xv[9];
#pragma unroll
        for (int k = 0; k < 9; k++) xv[k] = x[n * 9 + k];
        float as[4], ad[4];
#pragma unroll
        for (int h = 0; h < 4; h++) {
            float s = 0.f, d = 0.f;
#pragma unroll
            for (int k = 0; k < 9; k++) {
                s += xv[k] * wf[k * 4 + h];
                d += xv[k] * wf[36 + k * 4 + h];
            }
            as[h] = s; ad[h] = d;
        }
        f32x4* xp = (f32x4*)(xa + (size_t)n * 16);
        xp[0] = (f32x4){xv[0], xv[1], xv[2], xv[3]};
        xp[1] = (f32x4){xv[4], xv[5], xv[6], xv[7]};
        xp[2] = (f32x4){xv[8], as[0], as[1], as[2]};
        xp[3] = (f32x4){as[3], 0.f, 0.f, 0.f};
        *(f32x4*)(ad4 + (size_t)n * 4) = (f32x4){ad[0], ad[1], ad[2], ad[3]};
    } else if (b < PRE_PACKB_END) {
        int t = (b - PRE_NODE_END) * 256 + tid;
#pragma unroll
        for (int m = 0; m < 4; m++) {
            int idx = t * 4 + m;
            int k = idx >> 7, nn = idx & 127;
            wsB[(size_t)nn * 512 + k] = (__bf16)W2[(size_t)k * 128 + nn];
        }
    } else if (b < PRE_DEG_END) {
        int idx = (b - PRE_PACKB_END) * 256 + tid;
        if (idx < N_NODES) deg[idx] = 0;
    } else {
        int g = (b - PRE_DEG_END) * 256 + tid;
        if (g > N_GRAPHS) return;
        int lo = 0, hi = N_NODES;
        while (lo < hi) { int mid = (lo + hi) >> 1; if (batch[mid] < g) lo = mid + 1; else hi = mid; }
        gstart[g] = lo;
    }
}

// build per-dst bucket of src ids
__global__ void k_bucket(const int* __restrict__ ei, int* __restrict__ deg,
                         int* __restrict__ bucket) {
    int e = blockIdx.x * 256 + threadIdx.x;
    if (e >= N_EDGES) return;
    int s = ei[e], d = ei[N_EDGES + e];
    int slot = atomicAdd(&deg[d], 1);
    if (slot < CAP) bucket[d * CAP + slot] = s;
}

// Mega GEMM (R11 structure, reverted): half-K double pass, 3 blocks/CU (45 KB):
//   phase 0: fused layer-1 aggregation (2 thr per node-head)
//   per half: phase 1 h2=elu(agg@W1+b1) (W1 global, L2-hot) -> bf16 frag As;
//             phase 2 MFMA, breg[8] per half
//   epilogue: p2b(bf16) + asad2 via LDS cross-wave reduction
__global__ __launch_bounds__(512, 6) void k_gemm(
    const float* __restrict__ xa, const float* __restrict__ ad4,
    const int* __restrict__ deg, const int* __restrict__ bucket,
    const float* __restrict__ W1, const float* __restrict__ b1,
    const __bf16* __restrict__ wsB,
    const float* __restrict__ a_src2, const float* __restrict__ a_dst2,
    __bf16* __restrict__ p2b, float* __restrict__ asad2) {
    __shared__ __bf16 As[64 * 256];    // 32 KB, frag-major: tile t=rt*8+kg, lane*8
    __shared__ __bf16 AgT[64 * 72];    // 9.2 KB
    __shared__ float red2[64 * 16];    // 4 KB
    const int tid = threadIdx.x;
    const int lane = tid & 63;
    const int w = tid >> 6;
    const int i = lane & 15;
    const int q = lane >> 4;
    const int m0 = blockIdx.x * 64;

    // ---- phase 0: fused layer-1 aggregation, 2 threads per (node,head) ----
    {
        int nh = tid >> 1, sub = tid & 1;
        int r = nh >> 2, h = nh & 3;
        int n = m0 + r;
        float acc[9] = {};
        float z = 0.f;
        bool valid = (n < N_NODES);
        if (valid) {
            float ad = ad4[(size_t)n * 4 + h];
            int dg = deg[n];
            if (dg > CAP) dg = CAP;
            if (sub == 0) {  // self loop
                const f32x4* xp = (const f32x4*)(xa + (size_t)n * 16);
                f32x4 v0 = xp[0], v1 = xp[1], v2 = xp[2], v3 = xp[3];
                float asl = (h == 0) ? v2.y : (h == 1) ? v2.z : (h == 2) ? v2.w : v3.x;
                float e = __expf(lrelu(asl + ad));
                z += e;
                acc[0] += e * v0.x; acc[1] += e * v0.y; acc[2] += e * v0.z; acc[3] += e * v0.w;
                acc[4] += e * v1.x; acc[5] += e * v1.y; acc[6] += e * v1.z; acc[7] += e * v1.w;
                acc[8] += e * v2.x;
            }
            for (int j = sub; j < dg; j += 2) {
                int src = bucket[n * CAP + j];
                const f32x4* xp = (const f32x4*)(xa + (size_t)src * 16);
                f32x4 v0 = xp[0], v1 = xp[1], v2 = xp[2], v3 = xp[3];
                float asl = (h == 0) ? v2.y : (h == 1) ? v2.z : (h == 2) ? v2.w : v3.x;
                float e = __expf(lrelu(asl + ad));
                z += e;
                acc[0] += e * v0.x; acc[1] += e * v0.y; acc[2] += e * v0.z; acc[3] += e * v0.w;
                acc[4] += e * v1.x; acc[5] += e * v1.y; acc[6] += e * v1.z; acc[7] += e * v1.w;
                acc[8] += e * v2.x;
            }
        }
        z += __shfl_xor(z, 1);
#pragma unroll
        for (int k = 0; k < 9; k++) acc[k] += __shfl_xor(acc[k], 1);
        if (sub == 0) {
            float inv = valid ? 1.f / z : 0.f;
            bf16x8 p0;
#pragma unroll
            for (int k = 0; k < 8; k++) p0[k] = (__bf16)(acc[k] * inv);
            __bf16* dst = AgT + r * 72 + h * 16;
            *(bf16x8*)dst = p0;
            dst[8] = (__bf16)(acc[8] * inv);
        }
    }
    __syncthreads();

    f32x4 acc[4];
#pragma unroll
    for (int r = 0; r < 4; r++) acc[r] = (f32x4){0.f, 0.f, 0.f, 0.f};

    const int row = tid & 63;
    const int kg = __builtin_amdgcn_readfirstlane(tid >> 6);  // wave-uniform
    const int rt_p1 = row >> 4, il = row & 15;
    const __bf16* bcol = wsB + (size_t)(w * 16 + i) * 512 + q * 8;

#pragma unroll
    for (int half = 0; half < 2; half++) {
        bf16x8 breg[8];
#pragma unroll
        for (int kc = 0; kc < 8; kc++)
            breg[kc] = *(const bf16x8*)(bcol + half * 256 + kc * 32);

        // ---- phase 1: h2 for 256 cols; thread = (row, kg: 32-col group) ----
        {
            int h = half * 2 + (kg >> 2);
            float ag[9];
            {
                bf16x8 a8 = *(const bf16x8*)&AgT[row * 72 + h * 16];
#pragma unroll
                for (int k = 0; k < 8; k++) ag[k] = (float)a8[k];
                ag[8] = (float)AgT[row * 72 + h * 16 + 8];
            }
#pragma unroll
            for (int c8 = 0; c8 < 4; c8++) {
                int j0 = half * 256 + kg * 32 + c8 * 8;
                float o[8];
#pragma unroll
                for (int e = 0; e < 8; e++) o[e] = b1[j0 + e];
#pragma unroll
                for (int k = 0; k < 9; k++) {
                    const float* wp = &W1[k * 512 + j0];
#pragma unroll
                    for (int e = 0; e < 8; e++) o[e] += ag[k] * wp[e];
                }
                bf16x8 pk;
#pragma unroll
                for (int e = 0; e < 8; e++) pk[e] = (__bf16)elu(o[e]);
                *(bf16x8*)&As[(rt_p1 * 8 + kg) * 512 + (c8 * 16 + il) * 8] = pk;
            }
        }
        __syncthreads();

        // ---- phase 2: MFMA sweep over this half's 8 kc-tiles ----
#pragma unroll
        for (int kc = 0; kc < 8; kc++) {
#pragma unroll
            for (int rt = 0; rt < 4; rt++) {
                bf16x8 af = *(const bf16x8*)&As[(rt * 8 + kc) * 512 + lane * 8];
                acc[rt] = __builtin_amdgcn_mfma_f32_16x16x32_bf16(af, breg[kc], acc[rt], 0, 0, 0);
            }
        }
        __syncthreads();
    }

    // ---- epilogue: p2b + asad2 via LDS cross-wave reduction ----
    float as2 = a_src2[w * 16 + i];
    float ad2 = a_dst2[w * 16 + i];
#pragma unroll
    for (int rt = 0; rt < 4; rt++) {
#pragma unroll
        for (int qq = 0; qq < 4; qq++) {
            int r2 = rt * 16 + q * 4 + qq;
            float v = acc[rt][qq];
            if (m0 + r2 < N_NODES)
                p2b[(size_t)(m0 + r2) * 128 + w * 16 + i] = (__bf16)v;
            float s = v * as2, d = v * ad2;
#pragma unroll
            for (int off = 1; off < 16; off <<= 1) {
                s += __shfl_xor(s, off);
                d += __shfl_xor(d, off);
            }
            if (i == 0) {
                red2[r2 * 16 + w * 2] = s;
                red2[r2 * 16 + w * 2 + 1] = d;
            }
        }
    }
    __syncthreads();
    if (tid < 128) {
        int r2 = tid >> 1, cc = tid & 1;
        float sum = 0.f;
#pragma unroll
        for (int ww = 0; ww < 8; ww++) sum += red2[r2 * 16 + ww * 2 + cc];
        if (m0 + r2 < N_NODES) asad2[(size_t)(m0 + r2) * 2 + cc] = sum;
    }
}

// Layer-2 attention aggregation: ONE WAVE PER NODE (100K waves, max TLP),
// chunk-4 neighbor gathers, plain coalesced bf16 store of h3[n]. NO atomics.
__global__ void k_agg2(const __bf16* __restrict__ p2b, const float* __restrict__ asad2,
                       const int* __restrict__ deg, const int* __restrict__ bucket,
                       const float* __restrict__ b2, __bf16* __restrict__ h3b) {
    int n = (blockIdx.x * 256 + threadIdx.x) >> 6;
    n = __builtin_amdgcn_readfirstlane(n);
    if (n >= N_NODES) return;
    int lane = threadIdx.x & 63;
    float ad = asad2[n * 2 + 1];
    float e = __expf(lrelu(asad2[n * 2] + ad));  // self loop
    float z = e;
    bf16x2 v = ((const bf16x2*)(p2b + (size_t)n * 128))[lane];
    float a0 = e * (float)v.x;
    float a1 = e * (float)v.y;
    int dg = deg[n];
    if (dg > CAP) dg = CAP;
    for (int j = 0; j < dg; j += 4) {
        int s0 = bucket[n * CAP + j];
        int s1 = bucket[n * CAP + min(j + 1, dg - 1)];
        int s2 = bucket[n * CAP + min(j + 2, dg - 1)];
        int s3 = bucket[n * CAP + min(j + 3, dg - 1)];
        float l0 = asad2[s0 * 2], l1 = asad2[s1 * 2];
        float l2 = asad2[s2 * 2], l3 = asad2[s3 * 2];
        bf16x2 w0 = ((const bf16x2*)(p2b + (size_t)s0 * 128))[lane];
        bf16x2 w1 = ((const bf16x2*)(p2b + (size_t)s1 * 128))[lane];
        bf16x2 w2 = ((const bf16x2*)(p2b + (size_t)s2 * 128))[lane];
        bf16x2 w3 = ((const bf16x2*)(p2b + (size_t)s3 * 128))[lane];
        float e0 = __expf(lrelu(l0 + ad));
        float e1 = (j + 1 < dg) ? __expf(lrelu(l1 + ad)) : 0.f;
        float e2 = (j + 2 < dg) ? __expf(lrelu(l2 + ad)) : 0.f;
        float e3 = (j + 3 < dg) ? __expf(lrelu(l3 + ad)) : 0.f;
        z += e0 + e1 + e2 + e3;
        a0 += e0 * (float)w0.x + e1 * (float)w1.x + e2 * (float)w2.x + e3 * (float)w3.x;
        a1 += e0 * (float)w0.y + e1 * (float)w1.y + e2 * (float)w2.y + e3 * (float)w3.y;
    }
    float inv = 1.f / z;
    bf16x2 o;
    o.x = (__bf16)elu(a0 * inv + b2[2 * lane]);
    o.y = (__bf16)elu(a1 * inv + b2[2 * lane + 1]);
    ((bf16x2*)(h3b + (size_t)n * 128))[lane] = o;
}

// Graph mean-pool: one wave per graph, contiguous h3b rows (deeply pipelined
// independent loads, zero gathers), plain store of out[g].
__global__ void k_pool(const __bf16* __restrict__ h3b, const int* __restrict__ gstart,
                       float* __restrict__ out) {
    int g = (blockIdx.x * 256 + threadIdx.x) >> 6;
    g = __builtin_amdgcn_readfirstlane(g);
    if (g >= N_GRAPHS) return;
    int lane = threadIdx.x & 63;
    int s = gstart[g], e = gstart[g + 1];
    float a0 = 0.f, a1 = 0.f;
    for (int n = s; n < e; n++) {
        bf16x2 v = ((const bf16x2*)(h3b + (size_t)n * 128))[lane];
        a0 += (float)v.x;
        a1 += (float)v.y;
    }
    int cnt = e - s;
    float ic = (cnt > 0) ? 1.f / (float)cnt : 0.f;
    out[(size_t)g * 128 + 2 * lane] = a0 * ic;
    out[(size_t)g * 128 + 2 * lane + 1] = a1 * ic;
}

extern "C" void kernel_launch(void* const* d_in, const int* in_sizes, int n_in,
                              void* d_out, int out_size, void* d_ws, size_t ws_size,
                              hipStream_t stream) {
    const float* x       = (const float*)d_in[0];
    const int*   ei      = (const int*)d_in[1];
    const int*   batch   = (const int*)d_in[2];
    const float* W1      = (const float*)d_in[3];
    const float* a_src1  = (const float*)d_in[4];
    const float* a_dst1  = (const float*)d_in[5];
    const float* b1      = (const float*)d_in[6];
    const float* W2      = (const float*)d_in[7];
    const float* a_src2  = (const float*)d_in[8];
    const float* a_dst2  = (const float*)d_in[9];
    const float* b2      = (const float*)d_in[10];
    float* out = (float*)d_out;

    float* wsf   = (float*)d_ws;
    float* xa    = wsf + OFF_XA;
    float* ad4   = wsf + OFF_AD4;
    __bf16* p2b  = (__bf16*)(wsf + OFF_P2B);
    float* asad2 = wsf + OFF_ASAD2;
    __bf16* h3b  = (__bf16*)(wsf + OFF_H3B);
    __bf16* wsB  = (__bf16*)(wsf + OFF_WSB);
    int* gstart  = (int*)(wsf + OFF_GST);
    int* wsi    = (int*)(wsf + OFF_INT);
    int* deg    = wsi;
    int* bucket = wsi + N_NODES;

    k_pre<<<PRE_GST_END, 256, 0, stream>>>(x, W1, a_src1, a_dst1, W2, batch,
                                           xa, ad4, wsB, deg, gstart);
    k_bucket<<<(N_EDGES + 255) / 256, 256, 0, stream>>>(ei, deg, bucket);
    k_gemm<<<(N_NODES + 63) / 64, 512, 0, stream>>>(xa, ad4, deg, bucket, W1, b1,
                                                    wsB, a_src2, a_dst2, p2b, asad2);
    k_agg2<<<((size_t)N_NODES * 64 + 255) / 256, 256, 0, stream>>>(
        p2b, asad2, deg, bucket, b2, h3b);
    k_pool<<<(N_GRAPHS * 64) / 256, 256, 0, stream>>>(h3b, gstart, out);
}